// Round 4
// baseline (70.436 us; speedup 1.0000x reference)
//
#include <hip/hip_runtime.h>
#include <hip/hip_bf16.h>

// Problem constants (fixed by reference)
#define NB   32      // N  (batch)
#define CIN  32      // INC
#define COUT 32      // OUTC
#define INN_ 16384   // INN
#define ON   4096    // OUTN
#define MD   16      // MAXD

// ---------------------------------------------------------------------------
// Kernel 1: premix + transpose, bf16 output.
//   zT[n][j][c] = sum_i weight[i][c] * x[n][i][j]   (stored as bf16 pairs)
// Thread owns 4 consecutive j (float4 loads -> 1KB/wave-instr) and all 32 c
// (float4 acc[32] = 128 VGPR). i-chunks of 8, A/B double-buffered so 8 x 1KB
// loads are in flight under the 1024-FMA compute of the previous chunk.
// Grid: (INN/1024, N), block 256, 2 blocks/CU.
// ---------------------------------------------------------------------------
template <int BASE>
__device__ __forceinline__ void compute8(const float4 (&buf)[8],
                                         float4 (&acc)[COUT],
                                         const float* __restrict__ w) {
#pragma unroll
  for (int k = 0; k < 8; ++k) {
    const float4 xv = buf[k];
#pragma unroll
    for (int c = 0; c < COUT; ++c) {
      const float wv = w[(BASE + k) * COUT + c];  // uniform -> s_load
      acc[c].x += xv.x * wv;
      acc[c].y += xv.y * wv;
      acc[c].z += xv.z * wv;
      acc[c].w += xv.w * wv;
    }
  }
}

__global__ __launch_bounds__(256, 2) void premix_kernel(
    const float* __restrict__ x,
    const float* __restrict__ weight,
    unsigned* __restrict__ zT) {  // bf16x2 words, layout [n][j][c/2]
  const int n = blockIdx.y;
  const int j = blockIdx.x * 1024 + threadIdx.x * 4;

  // float4 view of x[n]; i-row stride = INN/4 = 4096 float4.
  const float4* xp = (const float4*)(x + (((size_t)n * CIN) << 14)) + (j >> 2);

  float4 acc[COUT];
#pragma unroll
  for (int c = 0; c < COUT; ++c) acc[c] = make_float4(0.f, 0.f, 0.f, 0.f);

  float4 bA[8], bB[8];
#pragma unroll
  for (int k = 0; k < 8; ++k) bA[k] = xp[(size_t)k * 4096];          // i 0..7
#pragma unroll
  for (int k = 0; k < 8; ++k) bB[k] = xp[(size_t)(k + 8) * 4096];    // i 8..15
  compute8<0>(bA, acc, weight);
#pragma unroll
  for (int k = 0; k < 8; ++k) bA[k] = xp[(size_t)(k + 16) * 4096];   // i 16..23
  compute8<8>(bB, acc, weight);
#pragma unroll
  for (int k = 0; k < 8; ++k) bB[k] = xp[(size_t)(k + 24) * 4096];   // i 24..31
  compute8<16>(bA, acc, weight);
  compute8<24>(bB, acc, weight);

  // Store 4 bf16 rows (j..j+3), 64B each, 256B contiguous per thread.
  unsigned* dst = zT + ((((size_t)(n << 14)) + j) << 4);  // 16 words/row

#define STORE_ROW(Q, COMP)                                         \
  {                                                                \
    unsigned wrow[16];                                             \
    _Pragma("unroll") for (int t = 0; t < 16; ++t) {               \
      __hip_bfloat162 h = __float22bfloat162_rn(                   \
          make_float2(acc[2 * t].COMP, acc[2 * t + 1].COMP));      \
      wrow[t] = *(unsigned*)&h;                                    \
    }                                                              \
    _Pragma("unroll") for (int u = 0; u < 4; ++u)                  \
        ((uint4*)(dst + (Q) * 16))[u] = ((uint4*)wrow)[u];         \
  }
  STORE_ROW(0, x)
  STORE_ROW(1, y)
  STORE_ROW(2, z)
  STORE_ROW(3, w)
#undef STORE_ROW
}

// ---------------------------------------------------------------------------
// Kernel 2: gather-pool + bias from bf16 zT.
//   out[n][c][o] = bias[c][o] + sum_{m<deg[o]} zT[n][A[o][m]][c]
// 16 lanes per o (each lane: one bf16x2 word = 2 channels); 4 o-streams per
// thread with fp32 register accumulators. A + degrees staged in LDS.
// Grid: 2048 blocks (XCD-swizzled), block 256. Each block: one n, 64 o.
// ---------------------------------------------------------------------------
__global__ __launch_bounds__(256) void gather_pool_kernel(
    const unsigned* __restrict__ zT,  // bf16x2 words, [n][j][c/2]
    const int* __restrict__ A,
    const float* __restrict__ mask,
    const float* __restrict__ bias,
    float* __restrict__ out) {
  __shared__ int   aIdx[64 * MD];    // 4 KB
  __shared__ int   degS[64];
  __shared__ float otile[COUT][65];  // (c+o)%32 banks: conflict-free

  // XCD-aware swizzle: block L -> XCD L%8; each XCD owns 4 consecutive n,
  // so zT[n] (1 MB bf16) stays L2-resident per XCD.
  const int L    = blockIdx.x;
  const int xcd  = L & 7;
  const int slot = L >> 3;                 // 0..255
  const int n    = xcd * 4 + (slot >> 6);  // 4 n per xcd
  const int o0   = (slot & 63) * 64;

  const int tid = threadIdx.x;

  // Stage A rows: 1024 ints, one int4 per thread, coalesced.
  ((int4*)aIdx)[tid] = ((const int4*)(A + o0 * MD))[tid];

  // Degrees: mask rows are exactly {1.0 x deg, 0.0 ...}.
  if (tid < 64) {
    const float4* mrow = (const float4*)(mask + (size_t)(o0 + tid) * MD);
    float s = 0.f;
#pragma unroll
    for (int q = 0; q < 4; ++q) {
      float4 v = mrow[q];
      s += v.x + v.y + v.z + v.w;
    }
    degS[tid] = (int)(s + 0.5f);
  }
  __syncthreads();

  const int l16 = tid & 15;  // channel pair index
  const int grp = tid >> 4;  // 0..15: group handles o = o0 + grp*4 + k

  const unsigned* zn = zT + (((size_t)n) << 18);  // zT[n]: 16384*16 words

  float2 acc[4];
  int    deg[4];
#pragma unroll
  for (int k = 0; k < 4; ++k) {
    acc[k] = make_float2(0.f, 0.f);
    deg[k] = degS[grp * 4 + k];
  }

#pragma unroll
  for (int m = 0; m < MD; ++m) {
#pragma unroll
    for (int k = 0; k < 4; ++k) {
      if (m < deg[k]) {  // uniform within 16-lane group
        const int idx = aIdx[(grp * 4 + k) * MD + m];
        const unsigned w = zn[idx * 16 + l16];  // 64B per group, coalesced
        acc[k].x += __uint_as_float(w << 16);
        acc[k].y += __uint_as_float(w & 0xffff0000u);
      }
    }
  }

#pragma unroll
  for (int k = 0; k < 4; ++k) {
    const int o = grp * 4 + k;
    otile[2 * l16][o]     = acc[k].x;
    otile[2 * l16 + 1][o] = acc[k].y;
  }
  __syncthreads();

  // Coalesced write + bias: lanes over o.
  const int ol = tid & 63;
  const int cg = (tid >> 6) * 8;
#pragma unroll
  for (int jj = 0; jj < 8; ++jj) {
    const int cc = cg + jj;
    out[((size_t)(n * COUT + cc)) * ON + o0 + ol] =
        otile[cc][ol] + bias[cc * ON + o0 + ol];
  }
}

// ---------------------------------------------------------------------------
// Fallback (ws too small): pool directly from x (strided gather), then mix.
// ---------------------------------------------------------------------------
__global__ __launch_bounds__(256) void fused_direct_kernel(
    const float* __restrict__ x,
    const int* __restrict__ A,
    const float* __restrict__ mask,
    const float* __restrict__ weight,
    const float* __restrict__ bias,
    float* __restrict__ out) {
  __shared__ float pooled[64][33];
  __shared__ float wl[CIN * COUT];

  const int n  = blockIdx.y;
  const int o0 = blockIdx.x * 64;
  const int tid = threadIdx.x;

  for (int k = tid; k < CIN * COUT; k += 256) wl[k] = weight[k];

  const int c = tid & 31;
  const int g = tid >> 5;
  for (int oo = g; oo < 64; oo += 8) {
    const int o = o0 + oo;
    float acc = 0.f;
#pragma unroll
    for (int m = 0; m < MD; ++m) {
      const float f = mask[o * MD + m];
      if (f == 0.f) break;
      const int idx = A[o * MD + m];
      acc += f * x[(((size_t)(n * CIN + c)) << 14) + idx];
    }
    pooled[oo][c] = acc;
  }
  __syncthreads();

  const int ol = tid & 63;
  const int cg = (tid >> 6) * 8;
  float y[8];
#pragma unroll
  for (int jj = 0; jj < 8; ++jj) y[jj] = bias[(cg + jj) * ON + o0 + ol];
  for (int i = 0; i < CIN; ++i) {
    const float p = pooled[ol][i];
#pragma unroll
    for (int jj = 0; jj < 8; ++jj) y[jj] += p * wl[i * 32 + cg + jj];
  }
#pragma unroll
  for (int jj = 0; jj < 8; ++jj)
    out[((size_t)(n * COUT + cg + jj)) * ON + o0 + ol] = y[jj];
}

extern "C" void kernel_launch(void* const* d_in, const int* in_sizes, int n_in,
                              void* d_out, int out_size, void* d_ws, size_t ws_size,
                              hipStream_t stream) {
  const float* x      = (const float*)d_in[0];
  const int*   A      = (const int*)d_in[1];
  const float* mask   = (const float*)d_in[2];
  const float* weight = (const float*)d_in[3];
  const float* bias   = (const float*)d_in[4];
  float* out = (float*)d_out;

  const size_t need = (size_t)NB * INN_ * COUT * sizeof(unsigned short);  // 32MB
  if (ws_size >= need) {
    unsigned* zT = (unsigned*)d_ws;
    premix_kernel<<<dim3(INN_ / 1024, NB), 256, 0, stream>>>(x, weight, zT);
    gather_pool_kernel<<<2048, 256, 0, stream>>>(zT, A, mask, bias, out);
  } else {
    fused_direct_kernel<<<dim3(ON / 64, NB), 256, 0, stream>>>(
        x, A, mask, weight, bias, out);
  }
}

// Round 5
// 57.712 us; speedup vs baseline: 1.2205x; 1.2205x over previous
//
#include <hip/hip_runtime.h>
#include <hip/hip_bf16.h>

// Problem constants (fixed by reference)
#define NB   32      // N  (batch)
#define CIN  32      // INC
#define COUT 32      // OUTC
#define INN_ 16384   // INN
#define ON   4096    // OUTN
#define MD   16      // MAXD

// ---------------------------------------------------------------------------
// Kernel 1: premix + transpose, bf16 output.
//   zT[n][j][c] = sum_i weight[i][c] * x[n][i][j]   (stored as bf16 pairs)
// LDS-staged: block stages x tile [32 i][256 j] (32.5 KB) with 8 coalesced
// dwordx4 loads/thread; then thread t owns column j0+t with acc[32] scalar
// fp32 (32 VGPR) -> ONE ds_read_b32 per 32 FMAs; weights stay wave-uniform
// (scalar pipe). Load latency paid once per block, hidden by 4 blocks/CU.
// Grid: (INN/256, N), block 256.
// ---------------------------------------------------------------------------
__global__ __launch_bounds__(256) void premix_kernel(
    const float* __restrict__ x,
    const float* __restrict__ weight,
    unsigned* __restrict__ zT) {  // bf16x2 words, layout [n][j][c/2]
  __shared__ float4 xs4[CIN][65];  // [i][j/4], row = 260 floats (pad 1 float4)

  const int n   = blockIdx.y;
  const int j0  = blockIdx.x * 256;
  const int tid = threadIdx.x;

  // Stage: 2048 float4 = 8 per thread, fully coalesced (1 KB / wave-instr).
  const float4* xv4 =
      (const float4*)(x + (((size_t)n * CIN) << 14) + j0);  // row stride 4096
  float4 stg[8];
#pragma unroll
  for (int r = 0; r < 8; ++r) {
    const int lin = r * 256 + tid;
    stg[r] = xv4[(size_t)(lin >> 6) * 4096 + (lin & 63)];
  }
#pragma unroll
  for (int r = 0; r < 8; ++r) {
    const int lin = r * 256 + tid;
    xs4[lin >> 6][lin & 63] = stg[r];
  }
  __syncthreads();

  // Compute: thread t -> column j = j0 + t, all 32 output channels.
  float acc[COUT];
#pragma unroll
  for (int c = 0; c < COUT; ++c) acc[c] = 0.f;

  const float* xsrow = (const float*)&xs4[0][0];  // row stride 260 floats
#pragma unroll
  for (int i = 0; i < CIN; ++i) {
    const float xv = xsrow[i * 260 + tid];  // stride-1 across lanes: no conflict
#pragma unroll
    for (int c = 0; c < COUT; ++c)
      acc[c] += xv * weight[i * COUT + c];  // uniform -> s_load, scalar pipe
  }

  // Pack to bf16 pairs and store 64 B contiguous per thread.
  unsigned wrow[16];
#pragma unroll
  for (int q = 0; q < 16; ++q) {
    __hip_bfloat162 h =
        __float22bfloat162_rn(make_float2(acc[2 * q], acc[2 * q + 1]));
    wrow[q] = *(unsigned*)&h;
  }
  uint4* dst = (uint4*)(zT + ((((size_t)(n << 14)) + j0 + tid) << 4));
#pragma unroll
  for (int u = 0; u < 4; ++u) dst[u] = ((uint4*)wrow)[u];
}

// ---------------------------------------------------------------------------
// Kernel 2: gather-pool + bias from bf16 zT.
//   out[n][c][o] = bias[c][o] + sum_{m<deg[o]} zT[n][A[o][m]][c]
// 16 lanes per o (each lane: one bf16x2 word = 2 channels); 4 o-streams per
// thread with fp32 register accumulators. A + degrees staged in LDS.
// Grid: 2048 blocks (XCD-swizzled), block 256. Each block: one n, 64 o.
// ---------------------------------------------------------------------------
__global__ __launch_bounds__(256) void gather_pool_kernel(
    const unsigned* __restrict__ zT,  // bf16x2 words, [n][j][c/2]
    const int* __restrict__ A,
    const float* __restrict__ mask,
    const float* __restrict__ bias,
    float* __restrict__ out) {
  __shared__ int   aIdx[64 * MD];    // 4 KB
  __shared__ int   degS[64];
  __shared__ float otile[COUT][65];  // (c+o)%32 banks: conflict-free

  // XCD-aware swizzle: block L -> XCD L%8; each XCD owns 4 consecutive n,
  // so zT[n] (1 MB bf16) stays L2-resident per XCD.
  const int L    = blockIdx.x;
  const int xcd  = L & 7;
  const int slot = L >> 3;                 // 0..255
  const int n    = xcd * 4 + (slot >> 6);  // 4 n per xcd
  const int o0   = (slot & 63) * 64;

  const int tid = threadIdx.x;

  // Stage A rows: 1024 ints, one int4 per thread, coalesced.
  ((int4*)aIdx)[tid] = ((const int4*)(A + o0 * MD))[tid];

  // Degrees: mask rows are exactly {1.0 x deg, 0.0 ...}.
  if (tid < 64) {
    const float4* mrow = (const float4*)(mask + (size_t)(o0 + tid) * MD);
    float s = 0.f;
#pragma unroll
    for (int q = 0; q < 4; ++q) {
      float4 v = mrow[q];
      s += v.x + v.y + v.z + v.w;
    }
    degS[tid] = (int)(s + 0.5f);
  }
  __syncthreads();

  const int l16 = tid & 15;  // channel pair index
  const int grp = tid >> 4;  // 0..15: group handles o = o0 + grp*4 + k

  const unsigned* zn = zT + (((size_t)n) << 18);  // zT[n]: 16384*16 words

  float2 acc[4];
  int    deg[4];
#pragma unroll
  for (int k = 0; k < 4; ++k) {
    acc[k] = make_float2(0.f, 0.f);
    deg[k] = degS[grp * 4 + k];
  }

#pragma unroll
  for (int m = 0; m < MD; ++m) {
#pragma unroll
    for (int k = 0; k < 4; ++k) {
      if (m < deg[k]) {  // uniform within 16-lane group
        const int idx = aIdx[(grp * 4 + k) * MD + m];
        const unsigned w = zn[idx * 16 + l16];  // 64B per group, coalesced
        acc[k].x += __uint_as_float(w << 16);
        acc[k].y += __uint_as_float(w & 0xffff0000u);
      }
    }
  }

#pragma unroll
  for (int k = 0; k < 4; ++k) {
    const int o = grp * 4 + k;
    otile[2 * l16][o]     = acc[k].x;
    otile[2 * l16 + 1][o] = acc[k].y;
  }
  __syncthreads();

  // Coalesced write + bias: lanes over o.
  const int ol = tid & 63;
  const int cg = (tid >> 6) * 8;
#pragma unroll
  for (int jj = 0; jj < 8; ++jj) {
    const int cc = cg + jj;
    out[((size_t)(n * COUT + cc)) * ON + o0 + ol] =
        otile[cc][ol] + bias[cc * ON + o0 + ol];
  }
}

// ---------------------------------------------------------------------------
// Fallback (ws too small): pool directly from x (strided gather), then mix.
// ---------------------------------------------------------------------------
__global__ __launch_bounds__(256) void fused_direct_kernel(
    const float* __restrict__ x,
    const int* __restrict__ A,
    const float* __restrict__ mask,
    const float* __restrict__ weight,
    const float* __restrict__ bias,
    float* __restrict__ out) {
  __shared__ float pooled[64][33];
  __shared__ float wl[CIN * COUT];

  const int n  = blockIdx.y;
  const int o0 = blockIdx.x * 64;
  const int tid = threadIdx.x;

  for (int k = tid; k < CIN * COUT; k += 256) wl[k] = weight[k];

  const int c = tid & 31;
  const int g = tid >> 5;
  for (int oo = g; oo < 64; oo += 8) {
    const int o = o0 + oo;
    float acc = 0.f;
#pragma unroll
    for (int m = 0; m < MD; ++m) {
      const float f = mask[o * MD + m];
      if (f == 0.f) break;
      const int idx = A[o * MD + m];
      acc += f * x[(((size_t)(n * CIN + c)) << 14) + idx];
    }
    pooled[oo][c] = acc;
  }
  __syncthreads();

  const int ol = tid & 63;
  const int cg = (tid >> 6) * 8;
  float y[8];
#pragma unroll
  for (int jj = 0; jj < 8; ++jj) y[jj] = bias[(cg + jj) * ON + o0 + ol];
  for (int i = 0; i < CIN; ++i) {
    const float p = pooled[ol][i];
#pragma unroll
    for (int jj = 0; jj < 8; ++jj) y[jj] += p * wl[i * 32 + cg + jj];
  }
#pragma unroll
  for (int jj = 0; jj < 8; ++jj)
    out[((size_t)(n * COUT + cg + jj)) * ON + o0 + ol] = y[jj];
}

extern "C" void kernel_launch(void* const* d_in, const int* in_sizes, int n_in,
                              void* d_out, int out_size, void* d_ws, size_t ws_size,
                              hipStream_t stream) {
  const float* x      = (const float*)d_in[0];
  const int*   A      = (const int*)d_in[1];
  const float* mask   = (const float*)d_in[2];
  const float* weight = (const float*)d_in[3];
  const float* bias   = (const float*)d_in[4];
  float* out = (float*)d_out;

  const size_t need = (size_t)NB * INN_ * COUT * sizeof(unsigned short);  // 32MB
  if (ws_size >= need) {
    unsigned* zT = (unsigned*)d_ws;
    premix_kernel<<<dim3(INN_ / 256, NB), 256, 0, stream>>>(x, weight, zT);
    gather_pool_kernel<<<2048, 256, 0, stream>>>(zT, A, mask, bias, out);
  } else {
    fused_direct_kernel<<<dim3(ON / 64, NB), 256, 0, stream>>>(
        x, A, mask, weight, bias, out);
  }
}

// Round 6
// 52.859 us; speedup vs baseline: 1.3325x; 1.0918x over previous
//
#include <hip/hip_runtime.h>
#include <hip/hip_bf16.h>

// Problem constants (fixed by reference)
#define NB   32      // N  (batch)
#define CIN  32      // INC
#define COUT 32      // OUTC
#define INN_ 16384   // INN
#define ON   4096    // OUTN
#define MD   16      // MAXD

// ---------------------------------------------------------------------------
// Kernel 1: premix + transpose, bf16 output.
//   zT[n][j][c] = sum_i weight[i][c] * x[n][i][j]   (stored as bf16 pairs)
// LDS-staged x tile [32 i][256 j] + LDS weights (4 KB). Inner loop per i:
// 1 ds_read_b32 (xv, stride-1) + 8 broadcast ds_read_b128 (weights, uniform
// address -> HW broadcast) + 32 FMA. All in-loop memory is in-order DS ops
// -> compiler pipelines with fine lgkmcnt(N); no SMEM/lgkm mixing stalls.
// Grid: (INN/256, N), block 256.
// ---------------------------------------------------------------------------
__global__ __launch_bounds__(256) void premix_kernel(
    const float* __restrict__ x,
    const float* __restrict__ weight,
    unsigned* __restrict__ zT) {  // bf16x2 words, layout [n][j][c/2]
  __shared__ float4 xs4[CIN][65];  // [i][j/4], row = 260 floats (pad 1 float4)
  __shared__ float4 wl4[CIN][8];   // weight row i, quad q = weight[i*32+4q..]

  const int n   = blockIdx.y;
  const int j0  = blockIdx.x * 256;
  const int tid = threadIdx.x;

  // Stage weights: 1024 floats = 256 float4, one per thread, coalesced.
  wl4[tid >> 3][tid & 7] = ((const float4*)weight)[tid];

  // Stage x: 2048 float4 = 8 per thread, fully coalesced (1 KB / wave-instr).
  const float4* xv4 =
      (const float4*)(x + (((size_t)n * CIN) << 14) + j0);  // row stride 4096
  float4 stg[8];
#pragma unroll
  for (int r = 0; r < 8; ++r) {
    const int lin = r * 256 + tid;
    stg[r] = xv4[(size_t)(lin >> 6) * 4096 + (lin & 63)];
  }
#pragma unroll
  for (int r = 0; r < 8; ++r) {
    const int lin = r * 256 + tid;
    xs4[lin >> 6][lin & 63] = stg[r];
  }
  __syncthreads();

  // Compute: thread t -> column j = j0 + t, all 32 output channels.
  float acc[COUT];
#pragma unroll
  for (int c = 0; c < COUT; ++c) acc[c] = 0.f;

  const float* xsrow = (const float*)&xs4[0][0];  // row stride 260 floats
#pragma unroll
  for (int i = 0; i < CIN; ++i) {
    const float xv = xsrow[i * 260 + tid];  // stride-1 across lanes
#pragma unroll
    for (int q = 0; q < 8; ++q) {
      const float4 wv = wl4[i][q];  // uniform addr -> broadcast ds_read_b128
      acc[4 * q + 0] += xv * wv.x;
      acc[4 * q + 1] += xv * wv.y;
      acc[4 * q + 2] += xv * wv.z;
      acc[4 * q + 3] += xv * wv.w;
    }
  }

  // Pack to bf16 pairs and store 64 B contiguous per thread.
  unsigned wrow[16];
#pragma unroll
  for (int q = 0; q < 16; ++q) {
    __hip_bfloat162 h =
        __float22bfloat162_rn(make_float2(acc[2 * q], acc[2 * q + 1]));
    wrow[q] = *(unsigned*)&h;
  }
  uint4* dst = (uint4*)(zT + ((((size_t)(n << 14)) + j0 + tid) << 4));
#pragma unroll
  for (int u = 0; u < 4; ++u) dst[u] = ((uint4*)wrow)[u];
}

// ---------------------------------------------------------------------------
// Kernel 2: gather-pool + bias from bf16 zT.
//   out[n][c][o] = bias[c][o] + sum_{m<deg[o]} zT[n][A[o][m]][c]
// 16 lanes per o (each lane: one bf16x2 word = 2 channels); 4 o-streams per
// thread with fp32 register accumulators. A + degrees staged in LDS.
// Grid: 2048 blocks (XCD-swizzled), block 256. Each block: one n, 64 o.
// ---------------------------------------------------------------------------
__global__ __launch_bounds__(256) void gather_pool_kernel(
    const unsigned* __restrict__ zT,  // bf16x2 words, [n][j][c/2]
    const int* __restrict__ A,
    const float* __restrict__ mask,
    const float* __restrict__ bias,
    float* __restrict__ out) {
  __shared__ int   aIdx[64 * MD];    // 4 KB
  __shared__ int   degS[64];
  __shared__ float otile[COUT][65];  // (c+o)%32 banks: conflict-free

  // XCD-aware swizzle: block L -> XCD L%8; each XCD owns 4 consecutive n,
  // so zT[n] (1 MB bf16) stays L2-resident per XCD.
  const int L    = blockIdx.x;
  const int xcd  = L & 7;
  const int slot = L >> 3;                 // 0..255
  const int n    = xcd * 4 + (slot >> 6);  // 4 n per xcd
  const int o0   = (slot & 63) * 64;

  const int tid = threadIdx.x;

  // Stage A rows: 1024 ints, one int4 per thread, coalesced.
  ((int4*)aIdx)[tid] = ((const int4*)(A + o0 * MD))[tid];

  // Degrees: mask rows are exactly {1.0 x deg, 0.0 ...}.
  if (tid < 64) {
    const float4* mrow = (const float4*)(mask + (size_t)(o0 + tid) * MD);
    float s = 0.f;
#pragma unroll
    for (int q = 0; q < 4; ++q) {
      float4 v = mrow[q];
      s += v.x + v.y + v.z + v.w;
    }
    degS[tid] = (int)(s + 0.5f);
  }
  __syncthreads();

  const int l16 = tid & 15;  // channel pair index
  const int grp = tid >> 4;  // 0..15: group handles o = o0 + grp*4 + k

  const unsigned* zn = zT + (((size_t)n) << 18);  // zT[n]: 16384*16 words

  float2 acc[4];
  int    deg[4];
#pragma unroll
  for (int k = 0; k < 4; ++k) {
    acc[k] = make_float2(0.f, 0.f);
    deg[k] = degS[grp * 4 + k];
  }

#pragma unroll
  for (int m = 0; m < MD; ++m) {
#pragma unroll
    for (int k = 0; k < 4; ++k) {
      if (m < deg[k]) {  // uniform within 16-lane group
        const int idx = aIdx[(grp * 4 + k) * MD + m];
        const unsigned w = zn[idx * 16 + l16];  // 64B per group, coalesced
        acc[k].x += __uint_as_float(w << 16);
        acc[k].y += __uint_as_float(w & 0xffff0000u);
      }
    }
  }

#pragma unroll
  for (int k = 0; k < 4; ++k) {
    const int o = grp * 4 + k;
    otile[2 * l16][o]     = acc[k].x;
    otile[2 * l16 + 1][o] = acc[k].y;
  }
  __syncthreads();

  // Coalesced write + bias: lanes over o.
  const int ol = tid & 63;
  const int cg = (tid >> 6) * 8;
#pragma unroll
  for (int jj = 0; jj < 8; ++jj) {
    const int cc = cg + jj;
    out[((size_t)(n * COUT + cc)) * ON + o0 + ol] =
        otile[cc][ol] + bias[cc * ON + o0 + ol];
  }
}

// ---------------------------------------------------------------------------
// Fallback (ws too small): pool directly from x (strided gather), then mix.
// ---------------------------------------------------------------------------
__global__ __launch_bounds__(256) void fused_direct_kernel(
    const float* __restrict__ x,
    const int* __restrict__ A,
    const float* __restrict__ mask,
    const float* __restrict__ weight,
    const float* __restrict__ bias,
    float* __restrict__ out) {
  __shared__ float pooled[64][33];
  __shared__ float wl[CIN * COUT];

  const int n  = blockIdx.y;
  const int o0 = blockIdx.x * 64;
  const int tid = threadIdx.x;

  for (int k = tid; k < CIN * COUT; k += 256) wl[k] = weight[k];

  const int c = tid & 31;
  const int g = tid >> 5;
  for (int oo = g; oo < 64; oo += 8) {
    const int o = o0 + oo;
    float acc = 0.f;
#pragma unroll
    for (int m = 0; m < MD; ++m) {
      const float f = mask[o * MD + m];
      if (f == 0.f) break;
      const int idx = A[o * MD + m];
      acc += f * x[(((size_t)(n * CIN + c)) << 14) + idx];
    }
    pooled[oo][c] = acc;
  }
  __syncthreads();

  const int ol = tid & 63;
  const int cg = (tid >> 6) * 8;
  float y[8];
#pragma unroll
  for (int jj = 0; jj < 8; ++jj) y[jj] = bias[(cg + jj) * ON + o0 + ol];
  for (int i = 0; i < CIN; ++i) {
    const float p = pooled[ol][i];
#pragma unroll
    for (int jj = 0; jj < 8; ++jj) y[jj] += p * wl[i * 32 + cg + jj];
  }
#pragma unroll
  for (int jj = 0; jj < 8; ++jj)
    out[((size_t)(n * COUT + cg + jj)) * ON + o0 + ol] = y[jj];
}

extern "C" void kernel_launch(void* const* d_in, const int* in_sizes, int n_in,
                              void* d_out, int out_size, void* d_ws, size_t ws_size,
                              hipStream_t stream) {
  const float* x      = (const float*)d_in[0];
  const int*   A      = (const int*)d_in[1];
  const float* mask   = (const float*)d_in[2];
  const float* weight = (const float*)d_in[3];
  const float* bias   = (const float*)d_in[4];
  float* out = (float*)d_out;

  const size_t need = (size_t)NB * INN_ * COUT * sizeof(unsigned short);  // 32MB
  if (ws_size >= need) {
    unsigned* zT = (unsigned*)d_ws;
    premix_kernel<<<dim3(INN_ / 256, NB), 256, 0, stream>>>(x, weight, zT);
    gather_pool_kernel<<<2048, 256, 0, stream>>>(zT, A, mask, bias, out);
  } else {
    fused_direct_kernel<<<dim3(ON / 64, NB), 256, 0, stream>>>(
        x, A, mask, weight, bias, out);
  }
}